// Round 1
// baseline (394.140 us; speedup 1.0000x reference)
//
#include <hip/hip_runtime.h>

#define NN 100000
#define NE 1200000
#define DIN 7
#define H 64
#define NG 64
#define NB_SCAN 98   // ceil(NN/1024)

// ---------------- CSR build ----------------
__global__ __launch_bounds__(256) void k_hist(const int* __restrict__ dst, int* __restrict__ cnt) {
    int e = blockIdx.x * 256 + threadIdx.x;
    if (e < NE) atomicAdd(&cnt[dst[e]], 1);
}

__global__ __launch_bounds__(256) void k_scan1(const int* __restrict__ cnt, int* __restrict__ partial) {
    int t = threadIdx.x, b = blockIdx.x;
    int base = b * 1024 + t * 4;
    int s = 0;
#pragma unroll
    for (int j = 0; j < 4; j++) { int i = base + j; if (i < NN) s += cnt[i]; }
    __shared__ int sd[256];
    sd[t] = s; __syncthreads();
    for (int off = 128; off > 0; off >>= 1) { if (t < off) sd[t] += sd[t + off]; __syncthreads(); }
    if (t == 0) partial[b] = sd[0];
}

__global__ void k_scan2(int* partial) {
    if (threadIdx.x == 0 && blockIdx.x == 0) {
        int run = 0;
        for (int i = 0; i < NB_SCAN; i++) { int v = partial[i]; partial[i] = run; run += v; }
        partial[NB_SCAN] = run;
    }
}

__global__ __launch_bounds__(256) void k_scan3(const int* __restrict__ cnt, const int* __restrict__ partial,
                                               int* __restrict__ row_ptr, int* __restrict__ cursor) {
    int t = threadIdx.x, b = blockIdx.x;
    int base = b * 1024 + t * 4;
    int v[4], pre[4], s = 0;
#pragma unroll
    for (int j = 0; j < 4; j++) { int i = base + j; v[j] = (i < NN) ? cnt[i] : 0; pre[j] = s; s += v[j]; }
    __shared__ int sd[256];
    sd[t] = s; __syncthreads();
    for (int off = 1; off < 256; off <<= 1) {
        int y = (t >= off) ? sd[t - off] : 0;
        __syncthreads();
        sd[t] += y;
        __syncthreads();
    }
    int excl = sd[t] - s + partial[b];
#pragma unroll
    for (int j = 0; j < 4; j++) {
        int i = base + j;
        if (i < NN) { int val = excl + pre[j]; row_ptr[i] = val; cursor[i] = val; }
    }
    if (b == 0 && t == 0) row_ptr[NN] = NE;
}

__global__ __launch_bounds__(256) void k_dinv(const int* __restrict__ cnt, float* __restrict__ dinv) {
    int v = blockIdx.x * 256 + threadIdx.x;
    if (v < NN) dinv[v] = rsqrtf((float)(cnt[v] + 1));  // +1 self-loop; deg>=1 always
}

__global__ __launch_bounds__(256) void k_scatter(const int* __restrict__ src, const int* __restrict__ dst,
                                                 int* __restrict__ cursor, int* __restrict__ col) {
    int e = blockIdx.x * 256 + threadIdx.x;
    if (e < NE) { int p = atomicAdd(&cursor[dst[e]], 1); col[p] = src[e]; }
}

// ---------------- input projection: h = relu(x @ W_in + b_in) ----------------
__global__ __launch_bounds__(256) void k_inproj(const float* __restrict__ x, const float* __restrict__ Win,
                                                const float* __restrict__ bin, float* __restrict__ h) {
    __shared__ float Ws[DIN * H];
    for (int j = threadIdx.x; j < DIN * H; j += 256) Ws[j] = Win[j];
    __syncthreads();
    int idx = blockIdx.x * 256 + threadIdx.x;   // grid sized exactly NN*H/256
    int r = idx >> 6, c = idx & 63;
    float acc = bin[c];
#pragma unroll
    for (int k = 0; k < DIN; k++) acc += x[r * DIN + k] * Ws[k * H + c];
    h[idx] = fmaxf(acc, 0.f);
}

// ---------------- hws = (h @ W) * dinv[row] ----------------
__global__ __launch_bounds__(256) void k_gemm_scale(const float* __restrict__ A, const float* __restrict__ W,
                                                    const float* __restrict__ dinv, float* __restrict__ out) {
    __shared__ float As[16][68];   // [k][row], stride 68 avoids bank conflicts
    __shared__ float Ws[16][64];   // [k][col]
    int tid = threadIdx.x;
    int r0 = blockIdx.x * 64;
    int tr = tid >> 4, tc = tid & 15;
    float acc[4][4] = {};
    for (int k0 = 0; k0 < H; k0 += 16) {
        int row = tid >> 2;
        int kk4 = (tid & 3) * 4;
        int gr = r0 + row;
        float4 av = make_float4(0.f, 0.f, 0.f, 0.f);
        if (gr < NN) av = *(const float4*)(A + gr * H + k0 + kk4);
        As[kk4 + 0][row] = av.x; As[kk4 + 1][row] = av.y;
        As[kk4 + 2][row] = av.z; As[kk4 + 3][row] = av.w;
        int wk = tid >> 4, wc4 = (tid & 15) * 4;
        *(float4*)&Ws[wk][wc4] = *(const float4*)(W + (k0 + wk) * H + wc4);
        __syncthreads();
#pragma unroll
        for (int kk = 0; kk < 16; kk++) {
            float a0 = As[kk][tr * 4 + 0], a1 = As[kk][tr * 4 + 1];
            float a2 = As[kk][tr * 4 + 2], a3 = As[kk][tr * 4 + 3];
            float4 bv = *(const float4*)&Ws[kk][tc * 4];
            acc[0][0] += a0 * bv.x; acc[0][1] += a0 * bv.y; acc[0][2] += a0 * bv.z; acc[0][3] += a0 * bv.w;
            acc[1][0] += a1 * bv.x; acc[1][1] += a1 * bv.y; acc[1][2] += a1 * bv.z; acc[1][3] += a1 * bv.w;
            acc[2][0] += a2 * bv.x; acc[2][1] += a2 * bv.y; acc[2][2] += a2 * bv.z; acc[2][3] += a2 * bv.w;
            acc[3][0] += a3 * bv.x; acc[3][1] += a3 * bv.y; acc[3][2] += a3 * bv.z; acc[3][3] += a3 * bv.w;
        }
        __syncthreads();
    }
#pragma unroll
    for (int i = 0; i < 4; i++) {
        int gr = r0 + tr * 4 + i;
        if (gr < NN) {
            float s = dinv[gr];
            float4 o = make_float4(acc[i][0] * s, acc[i][1] * s, acc[i][2] * s, acc[i][3] * s);
            *(float4*)(out + gr * H + tc * 4) = o;
        }
    }
}

// ---------------- fused aggregate + bias + BN + relu + residual ----------------
__global__ __launch_bounds__(256) void k_agg(const float* __restrict__ hws, const int* __restrict__ row_ptr,
                                             const int* __restrict__ col, const float* __restrict__ dinv,
                                             const float* __restrict__ cb, const float* __restrict__ gamma,
                                             const float* __restrict__ beta, const float* __restrict__ mean,
                                             const float* __restrict__ var, float* __restrict__ h, int layer) {
    int gtid = blockIdx.x * 256 + threadIdx.x;   // grid sized exactly NN/4 blocks
    int v = gtid >> 6;
    int lane = gtid & 63;
    float acc = hws[v * H + lane];               // self-loop contribution
    int s = row_ptr[v], e = row_ptr[v + 1];
    int i = s;
    for (; i + 4 <= e; i += 4) {
        int u0 = col[i], u1 = col[i + 1], u2 = col[i + 2], u3 = col[i + 3];
        acc += hws[u0 * H + lane];
        acc += hws[u1 * H + lane];
        acc += hws[u2 * H + lane];
        acc += hws[u3 * H + lane];
    }
    for (; i < e; ++i) acc += hws[col[i] * H + lane];
    float val = acc * dinv[v] + cb[lane];
    val = (val - mean[lane]) * rsqrtf(var[lane] + 1e-5f) * gamma[lane] + beta[lane];
    val = fmaxf(val, 0.f);
    if (layer) val += h[v * H + lane];
    h[v * H + lane] = val;
}

// ---------------- mean pool (batch is sorted) ----------------
#define POOL_CHUNK 128
__global__ __launch_bounds__(64) void k_pool(const float* __restrict__ h, const int* __restrict__ batch,
                                             float* __restrict__ sums, float* __restrict__ cntg) {
    int lane = threadIdx.x;
    int start = blockIdx.x * POOL_CHUNK;
    int end = start + POOL_CHUNK; if (end > NN) end = NN;
    float acc = 0.f, c = 0.f;
    int curg = batch[start];
    for (int n = start; n < end; ++n) {
        int g = batch[n];
        if (g != curg) {             // wave-uniform branch
            atomicAdd(&sums[curg * H + lane], acc);
            if (lane == 0) atomicAdd(&cntg[curg], c);
            acc = 0.f; c = 0.f; curg = g;
        }
        acc += h[n * H + lane];
        c += 1.f;
    }
    atomicAdd(&sums[curg * H + lane], acc);
    if (lane == 0) atomicAdd(&cntg[curg], c);
}

// ---------------- final MLP on pooled features ----------------
__global__ __launch_bounds__(64) void k_mlp(const float* __restrict__ sums, const float* __restrict__ cntg,
                                            const float* __restrict__ W1, const float* __restrict__ b1,
                                            const float* __restrict__ W2, const float* __restrict__ b2,
                                            float* __restrict__ out) {
    int g = threadIdx.x;
    float inv = 1.f / fmaxf(cntg[g], 1.f);
    float pooled[H];
#pragma unroll
    for (int k = 0; k < H; k++) pooled[k] = sums[g * H + k] * inv;
    float o = b2[0];
#pragma unroll
    for (int j = 0; j < H / 2; j++) {
        float z = b1[j];
#pragma unroll
        for (int k = 0; k < H; k++) z += pooled[k] * W1[k * (H / 2) + j];
        o += fmaxf(z, 0.f) * W2[j];
    }
    out[g] = o;
}

extern "C" void kernel_launch(void* const* d_in, const int* in_sizes, int n_in,
                              void* d_out, int out_size, void* d_ws, size_t ws_size,
                              hipStream_t stream) {
    const float* x     = (const float*)d_in[0];
    const int*   ei    = (const int*)d_in[1];
    const int*   batch = (const int*)d_in[2];
    const float* Win   = (const float*)d_in[3];
    const float* bin   = (const float*)d_in[4];
    const float* convW = (const float*)d_in[5];
    const float* convb = (const float*)d_in[6];
    const float* gamma = (const float*)d_in[7];
    const float* beta  = (const float*)d_in[8];
    const float* mean  = (const float*)d_in[9];
    const float* var   = (const float*)d_in[10];
    const float* W1    = (const float*)d_in[11];
    const float* b1    = (const float*)d_in[12];
    const float* W2    = (const float*)d_in[13];
    const float* b2    = (const float*)d_in[14];
    float* out = (float*)d_out;

    char* p = (char*)d_ws;
    auto alloc = [&](size_t bytes) -> void* {
        void* r = (void*)p;
        p += (bytes + 255) & ~(size_t)255;
        return r;
    };
    float* h       = (float*)alloc((size_t)NN * H * 4);
    float* hws     = (float*)alloc((size_t)NN * H * 4);
    float* dinv    = (float*)alloc((size_t)NN * 4);
    int*   cnt     = (int*)alloc((size_t)NN * 4);
    int*   row_ptr = (int*)alloc((size_t)(NN + 1) * 4);
    int*   cursor  = (int*)alloc((size_t)NN * 4);
    int*   partial = (int*)alloc((size_t)(NB_SCAN + 1) * 4);
    int*   col     = (int*)alloc((size_t)NE * 4);
    float* sums    = (float*)alloc((size_t)NG * H * 4);
    float* cntg    = (float*)alloc((size_t)NG * 4);

    const int* src  = ei;
    const int* dstp = ei + NE;

    hipMemsetAsync(cnt, 0, (size_t)NN * 4, stream);
    hipMemsetAsync(sums, 0, (size_t)NG * H * 4, stream);
    hipMemsetAsync(cntg, 0, (size_t)NG * 4, stream);

    k_hist<<<(NE + 255) / 256, 256, 0, stream>>>(dstp, cnt);
    k_scan1<<<NB_SCAN, 256, 0, stream>>>(cnt, partial);
    k_scan2<<<1, 64, 0, stream>>>(partial);
    k_scan3<<<NB_SCAN, 256, 0, stream>>>(cnt, partial, row_ptr, cursor);
    k_dinv<<<(NN + 255) / 256, 256, 0, stream>>>(cnt, dinv);
    k_scatter<<<(NE + 255) / 256, 256, 0, stream>>>(src, dstp, cursor, col);

    k_inproj<<<(NN * H) / 256, 256, 0, stream>>>(x, Win, bin, h);

    for (int l = 0; l < 2; l++) {
        k_gemm_scale<<<(NN + 63) / 64, 256, 0, stream>>>(h, convW + l * H * H, dinv, hws);
        k_agg<<<NN / 4, 256, 0, stream>>>(hws, row_ptr, col, dinv,
                                          convb + l * H, gamma + l * H, beta + l * H,
                                          mean + l * H, var + l * H, h, l);
    }

    k_pool<<<(NN + POOL_CHUNK - 1) / POOL_CHUNK, 64, 0, stream>>>(h, batch, sums, cntg);
    k_mlp<<<1, 64, 0, stream>>>(sums, cntg, W1, b1, W2, b2, out);
}

// Round 2
// 361.902 us; speedup vs baseline: 1.0891x; 1.0891x over previous
//
#include <hip/hip_runtime.h>

#define NN 100000
#define NE 1200000
#define DIN 7
#define H 64
#define NG 64
#define NB_SCAN 98   // ceil(NN/1024)

#define NTEAM 8            // one team per XCD (blockIdx % 8 round-robin heuristic)
#define NODES_PER_TEAM 12500
#define BPT 128            // blocks per team

// ---------------- CSR build (XCD-team versions) ----------------
// Each team only touches cnt/col regions for its 1/8 node range, so the
// random atomic/store targets stay resident in one XCD's L2 and write back
// as full lines instead of 1.2M partial-line HBM writes.
__global__ __launch_bounds__(256) void k_hist(const int* __restrict__ dst, int* __restrict__ cnt) {
    int team = blockIdx.x & 7;
    int blk  = blockIdx.x >> 3;
    int lo = team * NODES_PER_TEAM, hi = lo + NODES_PER_TEAM;
    for (int e = blk * 256 + threadIdx.x; e < NE; e += BPT * 256) {
        int d = dst[e];
        if (d >= lo && d < hi) atomicAdd(&cnt[d], 1);
    }
}

__global__ __launch_bounds__(256) void k_scan1(const int* __restrict__ cnt, int* __restrict__ partial) {
    int t = threadIdx.x, b = blockIdx.x;
    int base = b * 1024 + t * 4;
    int s = 0;
#pragma unroll
    for (int j = 0; j < 4; j++) { int i = base + j; if (i < NN) s += cnt[i]; }
    __shared__ int sd[256];
    sd[t] = s; __syncthreads();
    for (int off = 128; off > 0; off >>= 1) { if (t < off) sd[t] += sd[t + off]; __syncthreads(); }
    if (t == 0) partial[b] = sd[0];
}

__global__ void k_scan2(int* partial) {
    if (threadIdx.x == 0 && blockIdx.x == 0) {
        int run = 0;
        for (int i = 0; i < NB_SCAN; i++) { int v = partial[i]; partial[i] = run; run += v; }
        partial[NB_SCAN] = run;
    }
}

__global__ __launch_bounds__(256) void k_scan3(const int* __restrict__ cnt, const int* __restrict__ partial,
                                               int* __restrict__ row_ptr, int* __restrict__ cursor) {
    int t = threadIdx.x, b = blockIdx.x;
    int base = b * 1024 + t * 4;
    int v[4], pre[4], s = 0;
#pragma unroll
    for (int j = 0; j < 4; j++) { int i = base + j; v[j] = (i < NN) ? cnt[i] : 0; pre[j] = s; s += v[j]; }
    __shared__ int sd[256];
    sd[t] = s; __syncthreads();
    for (int off = 1; off < 256; off <<= 1) {
        int y = (t >= off) ? sd[t - off] : 0;
        __syncthreads();
        sd[t] += y;
        __syncthreads();
    }
    int excl = sd[t] - s + partial[b];
#pragma unroll
    for (int j = 0; j < 4; j++) {
        int i = base + j;
        if (i < NN) { int val = excl + pre[j]; row_ptr[i] = val; cursor[i] = val; }
    }
    if (b == 0 && t == 0) row_ptr[NN] = NE;
}

__global__ __launch_bounds__(256) void k_dinv(const int* __restrict__ cnt, float* __restrict__ dinv) {
    int v = blockIdx.x * 256 + threadIdx.x;
    if (v < NN) dinv[v] = rsqrtf((float)(cnt[v] + 1));  // +1 self-loop; deg>=1 always
}

__global__ __launch_bounds__(256) void k_scatter(const int* __restrict__ src, const int* __restrict__ dst,
                                                 int* __restrict__ cursor, int* __restrict__ col) {
    int team = blockIdx.x & 7;
    int blk  = blockIdx.x >> 3;
    int lo = team * NODES_PER_TEAM, hi = lo + NODES_PER_TEAM;
    for (int e = blk * 256 + threadIdx.x; e < NE; e += BPT * 256) {
        int d = dst[e];
        if (d >= lo && d < hi) {
            int p = atomicAdd(&cursor[d], 1);
            col[p] = src[e];
        }
    }
}

// ---------------- input projection: h = relu(x @ W_in + b_in) ----------------
__global__ __launch_bounds__(256) void k_inproj(const float* __restrict__ x, const float* __restrict__ Win,
                                                const float* __restrict__ bin, float* __restrict__ h) {
    __shared__ float Ws[DIN * H];
    for (int j = threadIdx.x; j < DIN * H; j += 256) Ws[j] = Win[j];
    __syncthreads();
    int idx = blockIdx.x * 256 + threadIdx.x;   // grid sized exactly NN*H/256
    int r = idx >> 6, c = idx & 63;
    float acc = bin[c];
#pragma unroll
    for (int k = 0; k < DIN; k++) acc += x[r * DIN + k] * Ws[k * H + c];
    h[idx] = fmaxf(acc, 0.f);
}

// ---------------- hws = (h @ W) * dinv[row] ----------------
__global__ __launch_bounds__(256) void k_gemm_scale(const float* __restrict__ A, const float* __restrict__ W,
                                                    const float* __restrict__ dinv, float* __restrict__ out) {
    __shared__ float As[16][68];   // [k][row], stride 68 avoids bank conflicts
    __shared__ float Ws[16][64];   // [k][col]
    int tid = threadIdx.x;
    int r0 = blockIdx.x * 64;
    int tr = tid >> 4, tc = tid & 15;
    float acc[4][4] = {};
    for (int k0 = 0; k0 < H; k0 += 16) {
        int row = tid >> 2;
        int kk4 = (tid & 3) * 4;
        int gr = r0 + row;
        float4 av = make_float4(0.f, 0.f, 0.f, 0.f);
        if (gr < NN) av = *(const float4*)(A + gr * H + k0 + kk4);
        As[kk4 + 0][row] = av.x; As[kk4 + 1][row] = av.y;
        As[kk4 + 2][row] = av.z; As[kk4 + 3][row] = av.w;
        int wk = tid >> 4, wc4 = (tid & 15) * 4;
        *(float4*)&Ws[wk][wc4] = *(const float4*)(W + (k0 + wk) * H + wc4);
        __syncthreads();
#pragma unroll
        for (int kk = 0; kk < 16; kk++) {
            float a0 = As[kk][tr * 4 + 0], a1 = As[kk][tr * 4 + 1];
            float a2 = As[kk][tr * 4 + 2], a3 = As[kk][tr * 4 + 3];
            float4 bv = *(const float4*)&Ws[kk][tc * 4];
            acc[0][0] += a0 * bv.x; acc[0][1] += a0 * bv.y; acc[0][2] += a0 * bv.z; acc[0][3] += a0 * bv.w;
            acc[1][0] += a1 * bv.x; acc[1][1] += a1 * bv.y; acc[1][2] += a1 * bv.z; acc[1][3] += a1 * bv.w;
            acc[2][0] += a2 * bv.x; acc[2][1] += a2 * bv.y; acc[2][2] += a2 * bv.z; acc[2][3] += a2 * bv.w;
            acc[3][0] += a3 * bv.x; acc[3][1] += a3 * bv.y; acc[3][2] += a3 * bv.z; acc[3][3] += a3 * bv.w;
        }
        __syncthreads();
    }
#pragma unroll
    for (int i = 0; i < 4; i++) {
        int gr = r0 + tr * 4 + i;
        if (gr < NN) {
            float s = dinv[gr];
            float4 o = make_float4(acc[i][0] * s, acc[i][1] * s, acc[i][2] * s, acc[i][3] * s);
            *(float4*)(out + gr * H + tc * 4) = o;
        }
    }
}

// ---------------- fused aggregate + bias + BN + relu + residual ----------------
__global__ __launch_bounds__(256) void k_agg(const float* __restrict__ hws, const int* __restrict__ row_ptr,
                                             const int* __restrict__ col, const float* __restrict__ dinv,
                                             const float* __restrict__ cb, const float* __restrict__ gamma,
                                             const float* __restrict__ beta, const float* __restrict__ mean,
                                             const float* __restrict__ var, float* __restrict__ h, int layer) {
    int gtid = blockIdx.x * 256 + threadIdx.x;   // grid sized exactly NN/4 blocks
    int v = gtid >> 6;
    int lane = gtid & 63;
    float acc = hws[v * H + lane];               // self-loop contribution
    int s = row_ptr[v], e = row_ptr[v + 1];
    int i = s;
    for (; i + 4 <= e; i += 4) {
        int u0 = col[i], u1 = col[i + 1], u2 = col[i + 2], u3 = col[i + 3];
        acc += hws[u0 * H + lane];
        acc += hws[u1 * H + lane];
        acc += hws[u2 * H + lane];
        acc += hws[u3 * H + lane];
    }
    for (; i < e; ++i) acc += hws[col[i] * H + lane];
    float val = acc * dinv[v] + cb[lane];
    val = (val - mean[lane]) * rsqrtf(var[lane] + 1e-5f) * gamma[lane] + beta[lane];
    val = fmaxf(val, 0.f);
    if (layer) val += h[v * H + lane];
    h[v * H + lane] = val;
}

// ---------------- mean pool (batch is sorted) ----------------
#define POOL_CHUNK 128
__global__ __launch_bounds__(64) void k_pool(const float* __restrict__ h, const int* __restrict__ batch,
                                             float* __restrict__ sums, float* __restrict__ cntg) {
    int lane = threadIdx.x;
    int start = blockIdx.x * POOL_CHUNK;
    int end = start + POOL_CHUNK; if (end > NN) end = NN;
    float acc = 0.f, c = 0.f;
    int curg = batch[start];
    for (int n = start; n < end; ++n) {
        int g = batch[n];
        if (g != curg) {             // wave-uniform branch
            atomicAdd(&sums[curg * H + lane], acc);
            if (lane == 0) atomicAdd(&cntg[curg], c);
            acc = 0.f; c = 0.f; curg = g;
        }
        acc += h[n * H + lane];
        c += 1.f;
    }
    atomicAdd(&sums[curg * H + lane], acc);
    if (lane == 0) atomicAdd(&cntg[curg], c);
}

// ---------------- final MLP on pooled features ----------------
__global__ __launch_bounds__(64) void k_mlp(const float* __restrict__ sums, const float* __restrict__ cntg,
                                            const float* __restrict__ W1, const float* __restrict__ b1,
                                            const float* __restrict__ W2, const float* __restrict__ b2,
                                            float* __restrict__ out) {
    int g = threadIdx.x;
    float inv = 1.f / fmaxf(cntg[g], 1.f);
    float pooled[H];
#pragma unroll
    for (int k = 0; k < H; k++) pooled[k] = sums[g * H + k] * inv;
    float o = b2[0];
#pragma unroll
    for (int j = 0; j < H / 2; j++) {
        float z = b1[j];
#pragma unroll
        for (int k = 0; k < H; k++) z += pooled[k] * W1[k * (H / 2) + j];
        o += fmaxf(z, 0.f) * W2[j];
    }
    out[g] = o;
}

extern "C" void kernel_launch(void* const* d_in, const int* in_sizes, int n_in,
                              void* d_out, int out_size, void* d_ws, size_t ws_size,
                              hipStream_t stream) {
    const float* x     = (const float*)d_in[0];
    const int*   ei    = (const int*)d_in[1];
    const int*   batch = (const int*)d_in[2];
    const float* Win   = (const float*)d_in[3];
    const float* bin   = (const float*)d_in[4];
    const float* convW = (const float*)d_in[5];
    const float* convb = (const float*)d_in[6];
    const float* gamma = (const float*)d_in[7];
    const float* beta  = (const float*)d_in[8];
    const float* mean  = (const float*)d_in[9];
    const float* var   = (const float*)d_in[10];
    const float* W1    = (const float*)d_in[11];
    const float* b1    = (const float*)d_in[12];
    const float* W2    = (const float*)d_in[13];
    const float* b2    = (const float*)d_in[14];
    float* out = (float*)d_out;

    char* p = (char*)d_ws;
    auto alloc = [&](size_t bytes) -> void* {
        void* r = (void*)p;
        p += (bytes + 255) & ~(size_t)255;
        return r;
    };
    float* h       = (float*)alloc((size_t)NN * H * 4);
    float* hws     = (float*)alloc((size_t)NN * H * 4);
    float* dinv    = (float*)alloc((size_t)NN * 4);
    int*   cnt     = (int*)alloc((size_t)NN * 4);
    int*   row_ptr = (int*)alloc((size_t)(NN + 1) * 4);
    int*   cursor  = (int*)alloc((size_t)NN * 4);
    int*   partial = (int*)alloc((size_t)(NB_SCAN + 1) * 4);
    int*   col     = (int*)alloc((size_t)NE * 4);
    float* sums    = (float*)alloc((size_t)NG * H * 4);
    float* cntg    = (float*)alloc((size_t)NG * 4);

    const int* src  = ei;
    const int* dstp = ei + NE;

    hipMemsetAsync(cnt, 0, (size_t)NN * 4, stream);
    hipMemsetAsync(sums, 0, (size_t)NG * H * 4, stream);
    hipMemsetAsync(cntg, 0, (size_t)NG * 4, stream);

    k_hist<<<NTEAM * BPT, 256, 0, stream>>>(dstp, cnt);
    k_scan1<<<NB_SCAN, 256, 0, stream>>>(cnt, partial);
    k_scan2<<<1, 64, 0, stream>>>(partial);
    k_scan3<<<NB_SCAN, 256, 0, stream>>>(cnt, partial, row_ptr, cursor);
    k_dinv<<<(NN + 255) / 256, 256, 0, stream>>>(cnt, dinv);
    k_scatter<<<NTEAM * BPT, 256, 0, stream>>>(src, dstp, cursor, col);

    k_inproj<<<(NN * H) / 256, 256, 0, stream>>>(x, Win, bin, h);

    for (int l = 0; l < 2; l++) {
        k_gemm_scale<<<(NN + 63) / 64, 256, 0, stream>>>(h, convW + l * H * H, dinv, hws);
        k_agg<<<NN / 4, 256, 0, stream>>>(hws, row_ptr, col, dinv,
                                          convb + l * H, gamma + l * H, beta + l * H,
                                          mean + l * H, var + l * H, h, l);
    }

    k_pool<<<(NN + POOL_CHUNK - 1) / POOL_CHUNK, 64, 0, stream>>>(h, batch, sums, cntg);
    k_mlp<<<1, 64, 0, stream>>>(sums, cntg, W1, b1, W2, b2, out);
}

// Round 3
// 344.561 us; speedup vs baseline: 1.1439x; 1.0503x over previous
//
#include <hip/hip_runtime.h>

#define NN 100000
#define NE 1200000
#define DIN 7
#define H 64
#define NG 64
#define NB_SCAN 98   // ceil(NN/1024)

#define NTEAM 8            // one team per XCD (blockIdx % 8 round-robin heuristic)
#define NODES_PER_TEAM 12500
#define BPT 128            // blocks per team

// bf16 helpers (RNE)
static __device__ __forceinline__ unsigned short f2bf(float f) {
    unsigned int u = __float_as_uint(f);
    unsigned int r = (u + 0x7fffu + ((u >> 16) & 1u)) >> 16;
    return (unsigned short)r;
}
static __device__ __forceinline__ float bf2f(unsigned short b) {
    return __uint_as_float((unsigned int)b << 16);
}

// ---------------- CSR build (XCD-team versions) ----------------
__global__ __launch_bounds__(256) void k_hist(const int* __restrict__ dst, int* __restrict__ cnt) {
    int team = blockIdx.x & 7;
    int blk  = blockIdx.x >> 3;
    int lo = team * NODES_PER_TEAM, hi = lo + NODES_PER_TEAM;
    for (int e = blk * 256 + threadIdx.x; e < NE; e += BPT * 256) {
        int d = dst[e];
        if (d >= lo && d < hi) atomicAdd(&cnt[d], 1);
    }
}

__global__ __launch_bounds__(256) void k_scan1(const int* __restrict__ cnt, int* __restrict__ partial) {
    int t = threadIdx.x, b = blockIdx.x;
    int base = b * 1024 + t * 4;
    int s = 0;
#pragma unroll
    for (int j = 0; j < 4; j++) { int i = base + j; if (i < NN) s += cnt[i]; }
    __shared__ int sd[256];
    sd[t] = s; __syncthreads();
    for (int off = 128; off > 0; off >>= 1) { if (t < off) sd[t] += sd[t + off]; __syncthreads(); }
    if (t == 0) partial[b] = sd[0];
}

__global__ void k_scan2(int* partial) {
    if (threadIdx.x == 0 && blockIdx.x == 0) {
        int run = 0;
        for (int i = 0; i < NB_SCAN; i++) { int v = partial[i]; partial[i] = run; run += v; }
        partial[NB_SCAN] = run;
    }
}

// scan3 also emits dinv (has cnt in registers already)
__global__ __launch_bounds__(256) void k_scan3(const int* __restrict__ cnt, const int* __restrict__ partial,
                                               int* __restrict__ row_ptr, int* __restrict__ cursor,
                                               float* __restrict__ dinv) {
    int t = threadIdx.x, b = blockIdx.x;
    int base = b * 1024 + t * 4;
    int v[4], pre[4], s = 0;
#pragma unroll
    for (int j = 0; j < 4; j++) { int i = base + j; v[j] = (i < NN) ? cnt[i] : 0; pre[j] = s; s += v[j]; }
    __shared__ int sd[256];
    sd[t] = s; __syncthreads();
    for (int off = 1; off < 256; off <<= 1) {
        int y = (t >= off) ? sd[t - off] : 0;
        __syncthreads();
        sd[t] += y;
        __syncthreads();
    }
    int excl = sd[t] - s + partial[b];
#pragma unroll
    for (int j = 0; j < 4; j++) {
        int i = base + j;
        if (i < NN) {
            int val = excl + pre[j];
            row_ptr[i] = val; cursor[i] = val;
            dinv[i] = rsqrtf((float)(v[j] + 1));   // +1 self-loop
        }
    }
    if (b == 0 && t == 0) row_ptr[NN] = NE;
}

__global__ __launch_bounds__(256) void k_scatter(const int* __restrict__ src, const int* __restrict__ dst,
                                                 int* __restrict__ cursor, int* __restrict__ col) {
    int team = blockIdx.x & 7;
    int blk  = blockIdx.x >> 3;
    int lo = team * NODES_PER_TEAM, hi = lo + NODES_PER_TEAM;
    for (int e = blk * 256 + threadIdx.x; e < NE; e += BPT * 256) {
        int d = dst[e];
        if (d >= lo && d < hi) {
            int p = atomicAdd(&cursor[d], 1);
            col[p] = src[e];
        }
    }
}

// ---------------- input projection: h = relu(x @ W_in + b_in) ----------------
__global__ __launch_bounds__(256) void k_inproj(const float* __restrict__ x, const float* __restrict__ Win,
                                                const float* __restrict__ bin, float* __restrict__ h) {
    __shared__ float Ws[DIN * H];
    for (int j = threadIdx.x; j < DIN * H; j += 256) Ws[j] = Win[j];
    __syncthreads();
    int idx = blockIdx.x * 256 + threadIdx.x;   // grid sized exactly NN*H/256
    int r = idx >> 6, c = idx & 63;
    float acc = bin[c];
#pragma unroll
    for (int k = 0; k < DIN; k++) acc += x[r * DIN + k] * Ws[k * H + c];
    h[idx] = fmaxf(acc, 0.f);
}

// ---------------- hws = bf16((h @ W) * dinv[row]) ----------------
__global__ __launch_bounds__(256) void k_gemm_scale(const float* __restrict__ A, const float* __restrict__ W,
                                                    const float* __restrict__ dinv,
                                                    unsigned short* __restrict__ out) {
    __shared__ float As[16][68];   // [k][row], stride 68 avoids bank conflicts
    __shared__ float Ws[16][64];   // [k][col]
    int tid = threadIdx.x;
    int r0 = blockIdx.x * 64;
    int tr = tid >> 4, tc = tid & 15;
    float acc[4][4] = {};
    for (int k0 = 0; k0 < H; k0 += 16) {
        int row = tid >> 2;
        int kk4 = (tid & 3) * 4;
        int gr = r0 + row;
        float4 av = make_float4(0.f, 0.f, 0.f, 0.f);
        if (gr < NN) av = *(const float4*)(A + gr * H + k0 + kk4);
        As[kk4 + 0][row] = av.x; As[kk4 + 1][row] = av.y;
        As[kk4 + 2][row] = av.z; As[kk4 + 3][row] = av.w;
        int wk = tid >> 4, wc4 = (tid & 15) * 4;
        *(float4*)&Ws[wk][wc4] = *(const float4*)(W + (k0 + wk) * H + wc4);
        __syncthreads();
#pragma unroll
        for (int kk = 0; kk < 16; kk++) {
            float a0 = As[kk][tr * 4 + 0], a1 = As[kk][tr * 4 + 1];
            float a2 = As[kk][tr * 4 + 2], a3 = As[kk][tr * 4 + 3];
            float4 bv = *(const float4*)&Ws[kk][tc * 4];
            acc[0][0] += a0 * bv.x; acc[0][1] += a0 * bv.y; acc[0][2] += a0 * bv.z; acc[0][3] += a0 * bv.w;
            acc[1][0] += a1 * bv.x; acc[1][1] += a1 * bv.y; acc[1][2] += a1 * bv.z; acc[1][3] += a1 * bv.w;
            acc[2][0] += a2 * bv.x; acc[2][1] += a2 * bv.y; acc[2][2] += a2 * bv.z; acc[2][3] += a2 * bv.w;
            acc[3][0] += a3 * bv.x; acc[3][1] += a3 * bv.y; acc[3][2] += a3 * bv.z; acc[3][3] += a3 * bv.w;
        }
        __syncthreads();
    }
#pragma unroll
    for (int i = 0; i < 4; i++) {
        int gr = r0 + tr * 4 + i;
        if (gr < NN) {
            float s = dinv[gr];
            ushort4 o;
            o.x = f2bf(acc[i][0] * s); o.y = f2bf(acc[i][1] * s);
            o.z = f2bf(acc[i][2] * s); o.w = f2bf(acc[i][3] * s);
            *(ushort4*)(out + gr * H + tc * 4) = o;
        }
    }
}

// ---------------- fused aggregate + bias + BN + relu + residual ----------------
__global__ __launch_bounds__(256) void k_agg(const unsigned short* __restrict__ hws,
                                             const int* __restrict__ row_ptr,
                                             const int* __restrict__ col, const float* __restrict__ dinv,
                                             const float* __restrict__ cb, const float* __restrict__ gamma,
                                             const float* __restrict__ beta, const float* __restrict__ mean,
                                             const float* __restrict__ var, float* __restrict__ h, int layer) {
    int gtid = blockIdx.x * 256 + threadIdx.x;   // grid sized exactly NN/4 blocks
    int v = gtid >> 6;
    int lane = gtid & 63;
    float acc = bf2f(hws[v * H + lane]);         // self-loop contribution
    int s = row_ptr[v], e = row_ptr[v + 1];
    int i = s;
    for (; i + 4 <= e; i += 4) {
        int u0 = col[i], u1 = col[i + 1], u2 = col[i + 2], u3 = col[i + 3];
        acc += bf2f(hws[u0 * H + lane]);
        acc += bf2f(hws[u1 * H + lane]);
        acc += bf2f(hws[u2 * H + lane]);
        acc += bf2f(hws[u3 * H + lane]);
    }
    for (; i < e; ++i) acc += bf2f(hws[col[i] * H + lane]);
    float val = acc * dinv[v] + cb[lane];
    val = (val - mean[lane]) * rsqrtf(var[lane] + 1e-5f) * gamma[lane] + beta[lane];
    val = fmaxf(val, 0.f);
    if (layer) val += h[v * H + lane];
    h[v * H + lane] = val;
}

// ---------------- mean pool (batch is sorted) ----------------
#define POOL_CHUNK 128
__global__ __launch_bounds__(64) void k_pool(const float* __restrict__ h, const int* __restrict__ batch,
                                             float* __restrict__ sums, float* __restrict__ cntg) {
    int lane = threadIdx.x;
    int start = blockIdx.x * POOL_CHUNK;
    int end = start + POOL_CHUNK; if (end > NN) end = NN;
    float acc = 0.f, c = 0.f;
    int curg = batch[start];
    for (int n = start; n < end; ++n) {
        int g = batch[n];
        if (g != curg) {             // wave-uniform branch
            atomicAdd(&sums[curg * H + lane], acc);
            if (lane == 0) atomicAdd(&cntg[curg], c);
            acc = 0.f; c = 0.f; curg = g;
        }
        acc += h[n * H + lane];
        c += 1.f;
    }
    atomicAdd(&sums[curg * H + lane], acc);
    if (lane == 0) atomicAdd(&cntg[curg], c);
}

// ---------------- final MLP on pooled features ----------------
__global__ __launch_bounds__(64) void k_mlp(const float* __restrict__ sums, const float* __restrict__ cntg,
                                            const float* __restrict__ W1, const float* __restrict__ b1,
                                            const float* __restrict__ W2, const float* __restrict__ b2,
                                            float* __restrict__ out) {
    int g = threadIdx.x;
    float inv = 1.f / fmaxf(cntg[g], 1.f);
    float pooled[H];
#pragma unroll
    for (int k = 0; k < H; k++) pooled[k] = sums[g * H + k] * inv;
    float o = b2[0];
#pragma unroll
    for (int j = 0; j < H / 2; j++) {
        float z = b1[j];
#pragma unroll
        for (int k = 0; k < H; k++) z += pooled[k] * W1[k * (H / 2) + j];
        o += fmaxf(z, 0.f) * W2[j];
    }
    out[g] = o;
}

extern "C" void kernel_launch(void* const* d_in, const int* in_sizes, int n_in,
                              void* d_out, int out_size, void* d_ws, size_t ws_size,
                              hipStream_t stream) {
    const float* x     = (const float*)d_in[0];
    const int*   ei    = (const int*)d_in[1];
    const int*   batch = (const int*)d_in[2];
    const float* Win   = (const float*)d_in[3];
    const float* bin   = (const float*)d_in[4];
    const float* convW = (const float*)d_in[5];
    const float* convb = (const float*)d_in[6];
    const float* gamma = (const float*)d_in[7];
    const float* beta  = (const float*)d_in[8];
    const float* mean  = (const float*)d_in[9];
    const float* var   = (const float*)d_in[10];
    const float* W1    = (const float*)d_in[11];
    const float* b1    = (const float*)d_in[12];
    const float* W2    = (const float*)d_in[13];
    const float* b2    = (const float*)d_in[14];
    float* out = (float*)d_out;

    char* p = (char*)d_ws;
    auto alloc = [&](size_t bytes) -> void* {
        void* r = (void*)p;
        p += (bytes + 255) & ~(size_t)255;
        return r;
    };
    float*          h       = (float*)alloc((size_t)NN * H * 4);
    unsigned short* hws     = (unsigned short*)alloc((size_t)NN * H * 2);
    float*          dinv    = (float*)alloc((size_t)NN * 4);
    int*            row_ptr = (int*)alloc((size_t)(NN + 1) * 4);
    int*            cursor  = (int*)alloc((size_t)NN * 4);
    int*            partial = (int*)alloc((size_t)(NB_SCAN + 1) * 4);
    int*            col     = (int*)alloc((size_t)NE * 4);
    // zero-initialized region (single memset spans cnt..cntg)
    int*            cnt     = (int*)alloc((size_t)NN * 4);
    float*          sums    = (float*)alloc((size_t)NG * H * 4);
    float*          cntg    = (float*)alloc((size_t)NG * 4);

    const int* src  = ei;
    const int* dstp = ei + NE;

    size_t zspan = (size_t)((char*)(cntg + NG) - (char*)cnt);
    hipMemsetAsync(cnt, 0, zspan, stream);

    k_hist<<<NTEAM * BPT, 256, 0, stream>>>(dstp, cnt);
    k_scan1<<<NB_SCAN, 256, 0, stream>>>(cnt, partial);
    k_scan2<<<1, 64, 0, stream>>>(partial);
    k_scan3<<<NB_SCAN, 256, 0, stream>>>(cnt, partial, row_ptr, cursor, dinv);
    k_scatter<<<NTEAM * BPT, 256, 0, stream>>>(src, dstp, cursor, col);

    k_inproj<<<(NN * H) / 256, 256, 0, stream>>>(x, Win, bin, h);

    for (int l = 0; l < 2; l++) {
        k_gemm_scale<<<(NN + 63) / 64, 256, 0, stream>>>(h, convW + l * H * H, dinv, hws);
        k_agg<<<NN / 4, 256, 0, stream>>>(hws, row_ptr, col, dinv,
                                          convb + l * H, gamma + l * H, beta + l * H,
                                          mean + l * H, var + l * H, h, l);
    }

    k_pool<<<(NN + POOL_CHUNK - 1) / POOL_CHUNK, 64, 0, stream>>>(h, batch, sums, cntg);
    k_mlp<<<1, 64, 0, stream>>>(sums, cntg, W1, b1, W2, b2, out);
}